// Round 1
// 691.065 us; speedup vs baseline: 1.3699x; 1.3699x over previous
//
#include <hip/hip_runtime.h>
#include <cstdint>
#include <climits>

// Problem constants (fixed by setup_inputs)
constexpr int kB = 2;
constexpr int kN = 100;
constexpr int kH = 640;
constexpr int kW = 640;
constexpr int kHW = kH * kW;          // 409600
constexpr int kWORDS = kHW / 64;      // 6400 u64 words per mask
constexpr int kD = 384;
constexpr int kFH = 40;
constexpr int kFW = 40;
constexpr int kC = 80;
constexpr int kC1 = kC + 1;           // 81
constexpr int kTOPK = 40;
constexpr int kCW = 2;                // conflict row words (ceil(100/64))

constexpr float MASK_THRESH = 0.4f;
constexpr float SCORE_THRESH = 0.35f;
constexpr float SUPPRESS_IOU = 0.85f;

// Output layout (concatenated flat, reference return order)
constexpr size_t O_MASK = 0;
constexpr size_t O_CLS  = (size_t)kB * kN * kHW;          // 81,920,000
constexpr size_t O_BOX  = O_CLS + (size_t)kB * kN * kC1;  // +16,200
constexpr size_t O_EMB  = O_BOX + (size_t)kB * kN * 4;    // +800

__device__ __forceinline__ float logitf_(float p) {
    p = fminf(fmaxf(p, 1e-4f), 1.0f - 1e-4f);
    return logf(p) - log1pf(-p);
}

// ---------------------------------------------------------------------------
// K0: per-image argsort by descending score (stable, LDS-staged), init
// area/bbox/confRow/denom. grid(kB), block(128)
__global__ void k0_sort_init(const float* __restrict__ scores,
                             const int* __restrict__ labels,
                             int* __restrict__ order, float* __restrict__ sScore,
                             int* __restrict__ sLabel, int* __restrict__ area,
                             int* __restrict__ bbox,
                             unsigned long long* __restrict__ confRow,
                             float* __restrict__ denom) {
    int b = blockIdx.x;
    int t = threadIdx.x;
    __shared__ float s[kN];
    if (t < kN) s[t] = scores[b * kN + t];
    __syncthreads();
    if (t < kN) {
        float si = s[t];
        int rank = 0;
        for (int j = 0; j < kN; ++j) {
            float sj = s[j];
            if (sj > si || (sj == si && j < t)) rank++;
        }
        order[b * kN + rank]  = t;
        sScore[b * kN + rank] = si;
        sLabel[b * kN + rank] = labels[b * kN + t];
        area[b * kN + t] = 0;
        bbox[(b * kN + t) * 4 + 0] = INT_MAX;  // xmin
        bbox[(b * kN + t) * 4 + 1] = INT_MIN;  // xmax
        bbox[(b * kN + t) * 4 + 2] = INT_MAX;  // ymin
        bbox[(b * kN + t) * 4 + 3] = INT_MIN;  // ymax
        confRow[(b * kN + t) * kCW + 0] = 0ull;
        confRow[(b * kN + t) * kCW + 1] = 0ull;
        if (t < kTOPK) denom[b * kTOPK + t] = 0.0f;
    }
}

// ---------------------------------------------------------------------------
// K1: bit-pack thresholded masks (sorted order) + area + bbox.
// grid(SPLIT=8, kN, kB), block(256). float4 loads (1 KB/wave/instr), 4 ballots
// per iteration. Bit order within the packed words is a fixed permutation of
// pixel order — safe because k2a only ANDs+popcounts pairs (permutation-
// invariant). bbox/area computed per-lane arithmetically + shfl reduce.
// Slots with sorted score < SCORE_THRESH can never be kept (greedy loop
// latches `stopped` at the first low score in descending order) — skip them.
constexpr int kSPLIT = 8;
__global__ __launch_bounds__(256) void k1_pack(
    const float* __restrict__ masks, const int* __restrict__ order,
    const float* __restrict__ sScore, unsigned long long* __restrict__ packed,
    int* __restrict__ area, int* __restrict__ bbox) {
    int b = blockIdx.z, slot = blockIdx.y;
    if (sScore[b * kN + slot] < SCORE_THRESH) return;  // provably never kept
    int q = order[b * kN + slot];
    const float4* src = (const float4*)(masks + (size_t)(b * kN + q) * kHW);
    unsigned long long* dst = packed + (size_t)(b * kN + slot) * (size_t)kWORDS;
    int lane = threadIdx.x & 63;
    int wv = threadIdx.x >> 6;
    const int wordsPerBlock = kWORDS / kSPLIT;  // 800
    const int wordsPerWave = wordsPerBlock / 4; // 200
    int wbase = blockIdx.x * wordsPerBlock + wv * wordsPerWave;
    int pixBase = wbase * 64;

    int areaAcc = 0;
    int x1 = INT_MAX, x2 = INT_MIN, y1 = INT_MAX, y2 = INT_MIN;
#pragma unroll 2
    for (int i = 0; i < wordsPerWave / 4; ++i) {   // 50 float4 iterations
        int pix = pixBase + i * 256 + lane * 4;    // 4 consecutive pixels
        float4 v = src[pix >> 2];
        bool p0 = v.x > MASK_THRESH, p1 = v.y > MASK_THRESH;
        bool p2 = v.z > MASK_THRESH, p3 = v.w > MASK_THRESH;
        unsigned long long b0 = __ballot(p0);
        unsigned long long b1 = __ballot(p1);
        unsigned long long b2 = __ballot(p2);
        unsigned long long b3 = __ballot(p3);
        if (lane == 0) {
            dst[wbase + 4 * i + 0] = b0;
            dst[wbase + 4 * i + 1] = b1;
            dst[wbase + 4 * i + 2] = b2;
            dst[wbase + 4 * i + 3] = b3;
        }
        int cnt = (int)p0 + (int)p1 + (int)p2 + (int)p3;
        areaAcc += cnt;
        if (cnt) {
            // 640 % 4 == 0 → the 4 pixels never straddle a row boundary
            int row  = pix / kW;
            int col0 = pix - row * kW;
            int lo = p0 ? 0 : (p1 ? 1 : (p2 ? 2 : 3));
            int hi = p3 ? 3 : (p2 ? 2 : (p1 ? 1 : 0));
            x1 = min(x1, col0 + lo); x2 = max(x2, col0 + hi);
            y1 = min(y1, row);       y2 = max(y2, row);
        }
    }
    // wave-level reduce
#pragma unroll
    for (int off = 32; off > 0; off >>= 1) {
        areaAcc += __shfl_down(areaAcc, off);
        x1 = min(x1, __shfl_down(x1, off));
        x2 = max(x2, __shfl_down(x2, off));
        y1 = min(y1, __shfl_down(y1, off));
        y2 = max(y2, __shfl_down(y2, off));
    }
    __shared__ int sA[4], sx1[4], sx2[4], sy1[4], sy2[4];
    if (lane == 0) { sA[wv] = areaAcc; sx1[wv] = x1; sx2[wv] = x2; sy1[wv] = y1; sy2[wv] = y2; }
    __syncthreads();
    if (threadIdx.x == 0) {
        int A   = sA[0] + sA[1] + sA[2] + sA[3];
        int bx1 = min(min(sx1[0], sx1[1]), min(sx1[2], sx1[3]));
        int bx2 = max(max(sx2[0], sx2[1]), max(sx2[2], sx2[3]));
        int by1 = min(min(sy1[0], sy1[1]), min(sy1[2], sy1[3]));
        int by2 = max(max(sy2[0], sy2[1]), max(sy2[2], sy2[3]));
        if (A) atomicAdd(&area[b * kN + slot], A);
        if (bx1 != INT_MAX) {
            atomicMin(&bbox[(b * kN + slot) * 4 + 0], bx1);
            atomicMax(&bbox[(b * kN + slot) * 4 + 1], bx2);
            atomicMin(&bbox[(b * kN + slot) * 4 + 2], by1);
            atomicMax(&bbox[(b * kN + slot) * 4 + 3], by2);
        }
    }
}

// ---------------------------------------------------------------------------
// K2a: conflict bit-rows (lower triangle). grid(kN, kN, kB), block(256).
// Scores are sorted descending, so sScore[j] >= sScore[i] for j < i: a single
// score check on i suffices to skip pairs whose packed data was never written.
__global__ __launch_bounds__(256) void k2a_conflict(
    const unsigned long long* __restrict__ packed,
    const int* __restrict__ sLabel, const float* __restrict__ sScore,
    const int* __restrict__ area, unsigned long long* __restrict__ confRow) {
    int i = blockIdx.x, j = blockIdx.y, b = blockIdx.z;
    if (j >= i) return;
    if (sScore[b * kN + i] < SCORE_THRESH) return;
    if (sLabel[b * kN + i] != sLabel[b * kN + j]) return;
    const unsigned long long* pi = packed + (size_t)(b * kN + i) * kWORDS;
    const unsigned long long* pj = packed + (size_t)(b * kN + j) * kWORDS;
    int acc = 0;
    for (int w = threadIdx.x; w < kWORDS; w += 256)
        acc += __popcll(pi[w] & pj[w]);
    __shared__ int s[256];
    s[threadIdx.x] = acc;
    __syncthreads();
    for (int st = 128; st > 0; st >>= 1) {
        if (threadIdx.x < st) s[threadIdx.x] += s[threadIdx.x + st];
        __syncthreads();
    }
    if (threadIdx.x == 0) {
        float inter = (float)s[0];
        float un = fmaxf((float)area[b * kN + i] + (float)area[b * kN + j] - inter, 1.0f);
        if (inter / un >= SUPPRESS_IOU)
            atomicOr(&confRow[(b * kN + i) * kCW + (j >> 6)], 1ull << (j & 63));
    }
}

// ---------------------------------------------------------------------------
// K2b: sequential greedy keep (lane 0, LDS-resident) + class_logits + boxes
// (formerly K4, merged — count/keep list already live in LDS). grid(kB),
// block(256).
__global__ __launch_bounds__(256) void k2b_greedy_clsbox(
    const float* __restrict__ sScore, const int* __restrict__ order,
    const unsigned long long* __restrict__ confRow,
    const int* __restrict__ sLabel, const int* __restrict__ area,
    const int* __restrict__ bbox, int* __restrict__ src_q,
    int* __restrict__ keep_s, int* __restrict__ countArr,
    float* __restrict__ out) {
    int b = blockIdx.x;
    int t = threadIdx.x;
    __shared__ float sc[kN];
    __shared__ int   ord[kN];
    __shared__ unsigned long long cr[kN * kCW];
    __shared__ int   ks[kN];
    __shared__ int   cnt_s;
    for (int e = t; e < kN; e += 256) {
        sc[e]  = sScore[b * kN + e];
        ord[e] = order[b * kN + e];
    }
    for (int e = t; e < kN * kCW; e += 256)
        cr[e] = confRow[(size_t)b * kN * kCW + e];
    __syncthreads();

    if (t == 0) {
        unsigned long long keptLo = 0ull, keptHi = 0ull;
        bool stopped = false;
        int count = 0;
        for (int i = 0; i < kN; ++i) {
            if (sc[i] < SCORE_THRESH) stopped = true;
            unsigned long long cl = cr[i * kCW + 0] & keptLo;
            unsigned long long ch = cr[i * kCW + 1] & keptHi;
            bool take = (!stopped) && ((cl | ch) == 0ull);
            if (take) {
                if (i < 64) keptLo |= 1ull << i; else keptHi |= 1ull << (i - 64);
                src_q[b * kN + count]  = ord[i];
                keep_s[b * kN + count] = i;
                ks[count] = i;
                count++;
                if (count >= kTOPK) stopped = true;
            }
        }
        countArr[b] = count;
        cnt_s = count;
        for (int s = count; s < kN; ++s) {
            src_q[b * kN + s] = -1; keep_s[b * kN + s] = -1; ks[s] = -1;
        }
    }
    __syncthreads();
    int count = cnt_s;

    // class_logits
    for (int e = t; e < kN * kC1; e += 256) {
        int slot = e / kC1, c = e % kC1;
        float val = -10.0f;
        if (slot < count) {
            int s2 = ks[slot];
            int lab = min(max(sLabel[b * kN + s2], 0), kC - 1);
            float scv = fminf(fmaxf(sc[s2], 0.f), 1.f);
            if (c == lab) val = logitf_(scv);
            else if (c == kC1 - 1) val = 0.0f;
        }
        out[O_CLS + (size_t)b * kN * kC1 + e] = val;
    }
    // boxes
    for (int slot = t; slot < kN; slot += 256) {
        float bx[4] = {0.f, 0.f, 0.f, 0.f};
        if (slot < count) {
            int s2 = ks[slot];
            if (area[b * kN + s2] > 0) {
                float x1 = (float)bbox[(b * kN + s2) * 4 + 0];
                float x2 = (float)bbox[(b * kN + s2) * 4 + 1];
                float y1 = (float)bbox[(b * kN + s2) * 4 + 2];
                float y2 = (float)bbox[(b * kN + s2) * 4 + 3];
                bx[0] = fminf(fmaxf((x1 + x2) * 0.5f / kW, 0.f), 1.f);
                bx[1] = fminf(fmaxf((y1 + y2) * 0.5f / kH, 0.f), 1.f);
                bx[2] = fminf(fmaxf(fmaxf(x2 - x1, 0.f) / kW, 0.f), 1.f);
                bx[3] = fminf(fmaxf(fmaxf(y2 - y1, 0.f) / kH, 0.f), 1.f);
            }
        }
        for (int c4 = 0; c4 < 4; ++c4)
            out[O_BOX + (size_t)(b * kN + slot) * 4 + c4] = bx[c4];
    }
}

// ---------------------------------------------------------------------------
// K3: mask_logits + fused x-resize (was K5). grid(kH/4, kN, kB), block(256):
// one wave per mask row. Kept slots: read row once (float4), write logits,
// stage clipped row in padded LDS (addr = col + col/32 breaks the 256B-stride
// 20-way bank conflict on the resize read), then lanes 0..39 produce the 40
// x-resize outputs (identical tap weights/order as the old k5 → bitwise-equal
// S1). Invalid slots: constant -20 fill, no mask read.
__global__ __launch_bounds__(256) void k3_logits_resizex(
    const float* __restrict__ masks, const int* __restrict__ src_q,
    float* __restrict__ out, float* __restrict__ S1) {
    int b = blockIdx.z, slot = blockIdx.y;
    int q = src_q[b * kN + slot];
    int lane = threadIdx.x & 63, wv = threadIdx.x >> 6;
    int y = blockIdx.x * 4 + wv;
    float4* dst = (float4*)(out + O_MASK + (size_t)(b * kN + slot) * kHW) + (size_t)y * 160;

    if (q < 0) {
        float4 f = make_float4(-20.f, -20.f, -20.f, -20.f);
        dst[lane] = f;
        dst[64 + lane] = f;
        if (lane < 32) dst[128 + lane] = f;
        return;
    }

    __shared__ float rbuf[4][660];  // 640 + 20 pad floats per row
    const float4* src = (const float4*)(masks + (size_t)(b * kN + q) * kHW) + (size_t)y * 160;
#pragma unroll
    for (int i = 0; i < 3; ++i) {
        int idx = i * 64 + lane;
        if (idx < 160) {
            float4 m = src[idx];
            float4 o;
            o.x = logitf_(m.x); o.y = logitf_(m.y);
            o.z = logitf_(m.z); o.w = logitf_(m.w);
            dst[idx] = o;
            int col = idx * 4;
            int pad = col >> 5;  // (col+c)>>5 == col>>5 for c in 0..3 (col%4==0)
            rbuf[wv][col + pad + 0] = fminf(fmaxf(m.x, 0.f), 1.f);
            rbuf[wv][col + pad + 1] = fminf(fmaxf(m.y, 0.f), 1.f);
            rbuf[wv][col + pad + 2] = fminf(fmaxf(m.z, 0.f), 1.f);
            rbuf[wv][col + pad + 3] = fminf(fmaxf(m.w, 0.f), 1.f);
        }
    }
    __syncthreads();
    if (lane < kFW) {
        int ox = lane;
        float c = 16.0f * ox + 7.5f;
        float s = 0.f;
#pragma unroll
        for (int t = 0; t < 32; ++t) {
            int j = 16 * ox - 8 + t;
            if (j >= 0 && j < kW) {
                float w = 1.0f - fabsf((float)j - c) * (1.0f / 16.0f);
                s += w * rbuf[wv][j + (j >> 5)];
            }
        }
        float rs = (ox == 0 || ox == kFW - 1) ? (1.0f / 14.0f) : (1.0f / 16.0f);
        // q>=0 implies slot < count <= kTOPK, so S1 indexing by slot is in-bounds
        S1[((size_t)(b * kTOPK + slot) * kH + y) * kFW + ox] = s * rs;
    }
}

// ---------------------------------------------------------------------------
// K6: resize along y (640 -> 40) + per-mask sum (denominator, via atomics —
// denom zero-initialized in K0, fmax applied at use in K7).
// grid(5, kTOPK, kB), block(256): 400 blocks (was 80 — under-occupied).
__global__ __launch_bounds__(256) void k6_resize_y(
    const float* __restrict__ S1, const int* __restrict__ countArr,
    float* __restrict__ msmall, float* __restrict__ denom) {
    int k = blockIdx.y, b = blockIdx.z;
    if (k >= countArr[b]) return;
    const float* src = S1 + (size_t)(b * kTOPK + k) * kH * kFW;
    int e0 = blockIdx.x * 320;
    float tot = 0.f;
    for (int ee = threadIdx.x; ee < 320; ee += 256) {
        int e = e0 + ee;
        int oy = e / kFW, ox = e % kFW;
        float c = 16.0f * oy + 7.5f;
        int j0 = max(0, 16 * oy - 8), j1 = min(kH - 1, 16 * oy + 23);
        float s = 0.f;
        for (int j = j0; j <= j1; ++j) {
            float w = 1.0f - fabsf((float)j - c) * (1.0f / 16.0f);
            s += w * src[(size_t)j * kFW + ox];
        }
        float rs = (oy == 0 || oy == kFH - 1) ? (1.0f / 14.0f) : (1.0f / 16.0f);
        s *= rs;
        msmall[(size_t)(b * kTOPK + k) * kFH * kFW + e] = s;
        tot += s;
    }
    __shared__ float sm[256];
    sm[threadIdx.x] = tot;
    __syncthreads();
    for (int st = 128; st > 0; st >>= 1) {
        if (threadIdx.x < st) sm[threadIdx.x] += sm[threadIdx.x + st];
        __syncthreads();
    }
    if (threadIdx.x == 0) atomicAdd(&denom[b * kTOPK + k], sm[0]);
}

// ---------------------------------------------------------------------------
// K7: mask-pooled features. grid(kD, kB), block(256): 4 waves per block, each
// wave caches the feature channel (25 regs/lane) and handles a k-stripe —
// 4x the waves/CU of the old 64-thread version.
__global__ __launch_bounds__(256) void k7_pool(
    const float* __restrict__ feat, const float* __restrict__ msmall,
    const float* __restrict__ denom, const int* __restrict__ countArr,
    float* __restrict__ pooled) {
    int d = blockIdx.x, b = blockIdx.y;
    int lane = threadIdx.x & 63, wv = threadIdx.x >> 6;
    const float* fp = feat + ((size_t)b * kD + d) * (kFH * kFW);
    float f[25];
#pragma unroll
    for (int i = 0; i < 25; ++i) f[i] = fp[i * 64 + lane];
    int count = countArr[b];
    for (int k = wv; k < count; k += 4) {
        const float* sp = msmall + (size_t)(b * kTOPK + k) * (kFH * kFW);
        float acc = 0.f;
#pragma unroll
        for (int i = 0; i < 25; ++i) acc += f[i] * sp[i * 64 + lane];
        for (int off = 32; off > 0; off >>= 1) acc += __shfl_down(acc, off);
        if (lane == 0)
            pooled[(size_t)(b * kTOPK + k) * kD + d] =
                acc / fmaxf(denom[b * kTOPK + k], 1e-6f);
    }
}

// ---------------------------------------------------------------------------
// K8: L2-normalize pooled -> embs (zeros for invalid). grid(kN, kB), block(128).
__global__ void k8_embs(const float* __restrict__ pooled,
                        const int* __restrict__ countArr,
                        float* __restrict__ out) {
    int slot = blockIdx.x, b = blockIdx.y;
    int count = countArr[b];
    float* dst = out + O_EMB + (size_t)(b * kN + slot) * kD;
    if (slot >= count) {
        for (int e = threadIdx.x; e < kD; e += 128) dst[e] = 0.f;
        return;
    }
    const float* p = pooled + (size_t)(b * kTOPK + slot) * kD;
    float ss = 0.f;
    for (int e = threadIdx.x; e < kD; e += 128) { float v = p[e]; ss += v * v; }
    __shared__ float sm[128];
    sm[threadIdx.x] = ss;
    __syncthreads();
    for (int st = 64; st > 0; st >>= 1) {
        if (threadIdx.x < st) sm[threadIdx.x] += sm[threadIdx.x + st];
        __syncthreads();
    }
    float norm = fmaxf(sqrtf(sm[0]), 1e-12f);
    for (int e = threadIdx.x; e < kD; e += 128) dst[e] = p[e] / norm;
}

// ---------------------------------------------------------------------------
extern "C" void kernel_launch(void* const* d_in, const int* in_sizes, int n_in,
                              void* d_out, int out_size, void* d_ws, size_t ws_size,
                              hipStream_t stream) {
    const float* masks  = (const float*)d_in[0];
    const int*   labels = (const int*)d_in[1];
    const float* scores = (const float*)d_in[2];
    const float* feat   = (const float*)d_in[3];
    // d_in[4] = class_count (device scalar) — fixed at 80 per problem shape.
    float* out = (float*)d_out;

    // Workspace carve-up (~19.1 MB total)
    char* ws = (char*)d_ws;
    auto take = [&](size_t bytes) { char* p = ws; ws += (bytes + 255) & ~(size_t)255; return p; };
    unsigned long long* packed = (unsigned long long*)take((size_t)kB * kN * kWORDS * 8);
    float* S1     = (float*)take((size_t)kB * kTOPK * kH * kFW * 4);
    float* msmall = (float*)take((size_t)kB * kTOPK * kFH * kFW * 4);
    float* pooled = (float*)take((size_t)kB * kTOPK * kD * 4);
    float* sScore = (float*)take((size_t)kB * kN * 4);
    float* denom  = (float*)take((size_t)kB * kTOPK * 4);
    int* order    = (int*)take((size_t)kB * kN * 4);
    int* sLabel   = (int*)take((size_t)kB * kN * 4);
    int* area     = (int*)take((size_t)kB * kN * 4);
    int* bbox     = (int*)take((size_t)kB * kN * 4 * 4);
    int* src_q    = (int*)take((size_t)kB * kN * 4);
    int* keep_s   = (int*)take((size_t)kB * kN * 4);
    int* countArr = (int*)take((size_t)kB * 4);
    unsigned long long* confRow = (unsigned long long*)take((size_t)kB * kN * kCW * 8);

    k0_sort_init<<<dim3(kB), dim3(128), 0, stream>>>(scores, labels, order, sScore,
                                                     sLabel, area, bbox, confRow, denom);
    k1_pack<<<dim3(kSPLIT, kN, kB), dim3(256), 0, stream>>>(masks, order, sScore,
                                                            packed, area, bbox);
    k2a_conflict<<<dim3(kN, kN, kB), dim3(256), 0, stream>>>(packed, sLabel, sScore,
                                                             area, confRow);
    k2b_greedy_clsbox<<<dim3(kB), dim3(256), 0, stream>>>(sScore, order, confRow,
                                                          sLabel, area, bbox, src_q,
                                                          keep_s, countArr, out);
    k3_logits_resizex<<<dim3(kH / 4, kN, kB), dim3(256), 0, stream>>>(masks, src_q,
                                                                      out, S1);
    k6_resize_y<<<dim3(5, kTOPK, kB), dim3(256), 0, stream>>>(S1, countArr, msmall,
                                                              denom);
    k7_pool<<<dim3(kD, kB), dim3(256), 0, stream>>>(feat, msmall, denom, countArr,
                                                    pooled);
    k8_embs<<<dim3(kN, kB), dim3(128), 0, stream>>>(pooled, countArr, out);
}

// Round 3
// 628.852 us; speedup vs baseline: 1.5055x; 1.0989x over previous
//
#include <hip/hip_runtime.h>
#include <cstdint>
#include <climits>

// Problem constants (fixed by setup_inputs)
constexpr int kB = 2;
constexpr int kN = 100;
constexpr int kH = 640;
constexpr int kW = 640;
constexpr int kHW = kH * kW;          // 409600
constexpr int kWORDS = kHW / 64;      // 6400 u64 words per mask
constexpr int kD = 384;
constexpr int kFH = 40;
constexpr int kFW = 40;
constexpr int kC = 80;
constexpr int kC1 = kC + 1;           // 81
constexpr int kTOPK = 40;
constexpr int kCW = 2;                // conflict row words (ceil(100/64))
constexpr int kPairMax = kN * (kN - 1) / 2;  // 4950

constexpr float MASK_THRESH = 0.4f;
constexpr float SCORE_THRESH = 0.35f;
constexpr float SUPPRESS_IOU = 0.85f;

// Output layout (concatenated flat, reference return order)
constexpr size_t O_MASK = 0;
constexpr size_t O_CLS  = (size_t)kB * kN * kHW;          // 81,920,000
constexpr size_t O_BOX  = O_CLS + (size_t)kB * kN * kC1;  // +16,200
constexpr size_t O_EMB  = O_BOX + (size_t)kB * kN * 4;    // +800

// Native clang vector type — __builtin_nontemporal_store rejects the HIP
// float4 class type but accepts ext_vector_type.
typedef float floatx4 __attribute__((ext_vector_type(4)));
__device__ __forceinline__ void nt_store4(const float4& v, float4* p) {
    floatx4 t; t.x = v.x; t.y = v.y; t.z = v.z; t.w = v.w;
    __builtin_nontemporal_store(t, (floatx4*)p);
}

// Precise version (cold paths: class_logits — 8.1K values)
__device__ __forceinline__ float logitf_(float p) {
    p = fminf(fmaxf(p, 1e-4f), 1.0f - 1e-4f);
    return logf(p) - log1pf(-p);
}

// Fast version (hot path: 32.8M mask-logit pixels). logit = ln(p/(1-p)).
// 1-p is exact where it matters (Sterbenz); __fdividef 2.5 ulp; v_log_f32
// ~1 ulp -> abs error < 1e-5 on a value of magnitude <= 9.21.
__device__ __forceinline__ float logit_fast(float p) {
    p = fminf(fmaxf(p, 1e-4f), 1.0f - 1e-4f);
    float r = __fdividef(p, 1.0f - p);
    return __log2f(r) * 0.69314718056f;
}

// ---------------------------------------------------------------------------
// K0: per-image argsort by descending score (stable, LDS-staged), init
// area/bbox/confRow/denom, and build the compact same-label candidate pair
// list consumed by K2a (i needs score>=thresh; j<i is then >=thresh too).
// grid(kB), block(128)
__global__ void k0_sort_init(const float* __restrict__ scores,
                             const int* __restrict__ labels,
                             int* __restrict__ order, float* __restrict__ sScore,
                             int* __restrict__ sLabel, int* __restrict__ area,
                             int* __restrict__ bbox,
                             unsigned long long* __restrict__ confRow,
                             float* __restrict__ denom,
                             int* __restrict__ pairList,
                             int* __restrict__ pairCount) {
    int b = blockIdx.x;
    int t = threadIdx.x;
    __shared__ float s[kN];
    __shared__ int   lb[kN];
    __shared__ float ssort[kN];
    __shared__ int   lsort[kN];
    if (t < kN) { s[t] = scores[b * kN + t]; lb[t] = labels[b * kN + t]; }
    if (t == 0) pairCount[b] = 0;
    __syncthreads();
    if (t < kN) {
        float si = s[t];
        int rank = 0;
        for (int j = 0; j < kN; ++j) {
            float sj = s[j];
            if (sj > si || (sj == si && j < t)) rank++;
        }
        order[b * kN + rank]  = t;
        sScore[b * kN + rank] = si;
        sLabel[b * kN + rank] = lb[t];
        ssort[rank] = si;
        lsort[rank] = lb[t];
        area[b * kN + t] = 0;
        bbox[(b * kN + t) * 4 + 0] = INT_MAX;  // xmin
        bbox[(b * kN + t) * 4 + 1] = INT_MIN;  // xmax
        bbox[(b * kN + t) * 4 + 2] = INT_MAX;  // ymin
        bbox[(b * kN + t) * 4 + 3] = INT_MIN;  // ymax
        confRow[(b * kN + t) * kCW + 0] = 0ull;
        confRow[(b * kN + t) * kCW + 1] = 0ull;
        if (t < kTOPK) denom[b * kTOPK + t] = 0.0f;
    }
    __syncthreads();
    // enumerate candidate pairs (j < i, same label, score[i] >= thresh)
    for (int idx = t; idx < kN * kN; idx += 128) {
        int i = idx / kN, j = idx - i * kN;
        if (j < i && lsort[i] == lsort[j] && ssort[i] >= SCORE_THRESH) {
            int pos = atomicAdd(&pairCount[b], 1);
            pairList[b * kPairMax + pos] = (i << 16) | j;
        }
    }
}

// ---------------------------------------------------------------------------
// K1: bit-pack thresholded masks (sorted order) + area + bbox.
// grid(SPLIT=8, kN, kB), block(256). float4 loads (1 KB/wave/instr), 4 ballots
// per iteration. Bit order within the packed words is a fixed permutation of
// pixel order — safe because k2a only ANDs+popcounts pairs (permutation-
// invariant). bbox/area computed per-lane arithmetically + shfl reduce.
// Slots with sorted score < SCORE_THRESH can never be kept (greedy loop
// latches `stopped` at the first low score in descending order) — skip them.
constexpr int kSPLIT = 8;
__global__ __launch_bounds__(256) void k1_pack(
    const float* __restrict__ masks, const int* __restrict__ order,
    const float* __restrict__ sScore, unsigned long long* __restrict__ packed,
    int* __restrict__ area, int* __restrict__ bbox) {
    int b = blockIdx.z, slot = blockIdx.y;
    if (sScore[b * kN + slot] < SCORE_THRESH) return;  // provably never kept
    int q = order[b * kN + slot];
    const float4* src = (const float4*)(masks + (size_t)(b * kN + q) * kHW);
    unsigned long long* dst = packed + (size_t)(b * kN + slot) * (size_t)kWORDS;
    int lane = threadIdx.x & 63;
    int wv = threadIdx.x >> 6;
    const int wordsPerBlock = kWORDS / kSPLIT;  // 800
    const int wordsPerWave = wordsPerBlock / 4; // 200
    int wbase = blockIdx.x * wordsPerBlock + wv * wordsPerWave;
    int pixBase = wbase * 64;

    int areaAcc = 0;
    int x1 = INT_MAX, x2 = INT_MIN, y1 = INT_MAX, y2 = INT_MIN;
#pragma unroll 2
    for (int i = 0; i < wordsPerWave / 4; ++i) {   // 50 float4 iterations
        int pix = pixBase + i * 256 + lane * 4;    // 4 consecutive pixels
        float4 v = src[pix >> 2];
        bool p0 = v.x > MASK_THRESH, p1 = v.y > MASK_THRESH;
        bool p2 = v.z > MASK_THRESH, p3 = v.w > MASK_THRESH;
        unsigned long long b0 = __ballot(p0);
        unsigned long long b1 = __ballot(p1);
        unsigned long long b2 = __ballot(p2);
        unsigned long long b3 = __ballot(p3);
        if (lane == 0) {
            dst[wbase + 4 * i + 0] = b0;
            dst[wbase + 4 * i + 1] = b1;
            dst[wbase + 4 * i + 2] = b2;
            dst[wbase + 4 * i + 3] = b3;
        }
        int cnt = (int)p0 + (int)p1 + (int)p2 + (int)p3;
        areaAcc += cnt;
        if (cnt) {
            // 640 % 4 == 0 → the 4 pixels never straddle a row boundary
            int row  = pix / kW;
            int col0 = pix - row * kW;
            int lo = p0 ? 0 : (p1 ? 1 : (p2 ? 2 : 3));
            int hi = p3 ? 3 : (p2 ? 2 : (p1 ? 1 : 0));
            x1 = min(x1, col0 + lo); x2 = max(x2, col0 + hi);
            y1 = min(y1, row);       y2 = max(y2, row);
        }
    }
    // wave-level reduce
#pragma unroll
    for (int off = 32; off > 0; off >>= 1) {
        areaAcc += __shfl_down(areaAcc, off);
        x1 = min(x1, __shfl_down(x1, off));
        x2 = max(x2, __shfl_down(x2, off));
        y1 = min(y1, __shfl_down(y1, off));
        y2 = max(y2, __shfl_down(y2, off));
    }
    __shared__ int sA[4], sx1[4], sx2[4], sy1[4], sy2[4];
    if (lane == 0) { sA[wv] = areaAcc; sx1[wv] = x1; sx2[wv] = x2; sy1[wv] = y1; sy2[wv] = y2; }
    __syncthreads();
    if (threadIdx.x == 0) {
        int A   = sA[0] + sA[1] + sA[2] + sA[3];
        int bx1 = min(min(sx1[0], sx1[1]), min(sx1[2], sx1[3]));
        int bx2 = max(max(sx2[0], sx2[1]), max(sx2[2], sx2[3]));
        int by1 = min(min(sy1[0], sy1[1]), min(sy1[2], sy1[3]));
        int by2 = max(max(sy2[0], sy2[1]), max(sy2[2], sy2[3]));
        if (A) atomicAdd(&area[b * kN + slot], A);
        if (bx1 != INT_MAX) {
            atomicMin(&bbox[(b * kN + slot) * 4 + 0], bx1);
            atomicMax(&bbox[(b * kN + slot) * 4 + 1], bx2);
            atomicMin(&bbox[(b * kN + slot) * 4 + 2], by1);
            atomicMax(&bbox[(b * kN + slot) * 4 + 3], by2);
        }
    }
}

// ---------------------------------------------------------------------------
// K2a: conflict bit-rows over the compact pair list (grid-stride; expected
// ~40 pairs/image, worst-case 4950). grid(512, kB), block(256).
__global__ __launch_bounds__(256) void k2a_conflict(
    const unsigned long long* __restrict__ packed,
    const int* __restrict__ area, const int* __restrict__ pairList,
    const int* __restrict__ pairCount, unsigned long long* __restrict__ confRow) {
    int b = blockIdx.y;
    int np = pairCount[b];
    __shared__ int s[256];
    for (int p = blockIdx.x; p < np; p += gridDim.x) {
        int pr = pairList[b * kPairMax + p];
        int i = pr >> 16, j = pr & 0xffff;
        const unsigned long long* pi = packed + (size_t)(b * kN + i) * kWORDS;
        const unsigned long long* pj = packed + (size_t)(b * kN + j) * kWORDS;
        int acc = 0;
        for (int w = threadIdx.x; w < kWORDS; w += 256)
            acc += __popcll(pi[w] & pj[w]);
        s[threadIdx.x] = acc;
        __syncthreads();
        for (int st = 128; st > 0; st >>= 1) {
            if (threadIdx.x < st) s[threadIdx.x] += s[threadIdx.x + st];
            __syncthreads();
        }
        if (threadIdx.x == 0) {
            float inter = (float)s[0];
            float un = fmaxf((float)area[b * kN + i] + (float)area[b * kN + j] - inter, 1.0f);
            if (inter / un >= SUPPRESS_IOU)
                atomicOr(&confRow[(b * kN + i) * kCW + (j >> 6)], 1ull << (j & 63));
        }
        __syncthreads();  // protect s[] before next pair
    }
}

// ---------------------------------------------------------------------------
// K2b: sequential greedy keep (lane 0, LDS-resident) + class_logits + boxes.
// grid(kB), block(256).
__global__ __launch_bounds__(256) void k2b_greedy_clsbox(
    const float* __restrict__ sScore, const int* __restrict__ order,
    const unsigned long long* __restrict__ confRow,
    const int* __restrict__ sLabel, const int* __restrict__ area,
    const int* __restrict__ bbox, int* __restrict__ src_q,
    int* __restrict__ keep_s, int* __restrict__ countArr,
    float* __restrict__ out) {
    int b = blockIdx.x;
    int t = threadIdx.x;
    __shared__ float sc[kN];
    __shared__ int   ord[kN];
    __shared__ unsigned long long cr[kN * kCW];
    __shared__ int   ks[kN];
    __shared__ int   cnt_s;
    for (int e = t; e < kN; e += 256) {
        sc[e]  = sScore[b * kN + e];
        ord[e] = order[b * kN + e];
    }
    for (int e = t; e < kN * kCW; e += 256)
        cr[e] = confRow[(size_t)b * kN * kCW + e];
    __syncthreads();

    if (t == 0) {
        unsigned long long keptLo = 0ull, keptHi = 0ull;
        bool stopped = false;
        int count = 0;
        for (int i = 0; i < kN; ++i) {
            if (sc[i] < SCORE_THRESH) stopped = true;
            unsigned long long cl = cr[i * kCW + 0] & keptLo;
            unsigned long long ch = cr[i * kCW + 1] & keptHi;
            bool take = (!stopped) && ((cl | ch) == 0ull);
            if (take) {
                if (i < 64) keptLo |= 1ull << i; else keptHi |= 1ull << (i - 64);
                src_q[b * kN + count]  = ord[i];
                keep_s[b * kN + count] = i;
                ks[count] = i;
                count++;
                if (count >= kTOPK) stopped = true;
            }
        }
        countArr[b] = count;
        cnt_s = count;
        for (int s = count; s < kN; ++s) {
            src_q[b * kN + s] = -1; keep_s[b * kN + s] = -1; ks[s] = -1;
        }
    }
    __syncthreads();
    int count = cnt_s;

    // class_logits
    for (int e = t; e < kN * kC1; e += 256) {
        int slot = e / kC1, c = e % kC1;
        float val = -10.0f;
        if (slot < count) {
            int s2 = ks[slot];
            int lab = min(max(sLabel[b * kN + s2], 0), kC - 1);
            float scv = fminf(fmaxf(sc[s2], 0.f), 1.f);
            if (c == lab) val = logitf_(scv);
            else if (c == kC1 - 1) val = 0.0f;
        }
        out[O_CLS + (size_t)b * kN * kC1 + e] = val;
    }
    // boxes
    for (int slot = t; slot < kN; slot += 256) {
        float bx[4] = {0.f, 0.f, 0.f, 0.f};
        if (slot < count) {
            int s2 = ks[slot];
            if (area[b * kN + s2] > 0) {
                float x1 = (float)bbox[(b * kN + s2) * 4 + 0];
                float x2 = (float)bbox[(b * kN + s2) * 4 + 1];
                float y1 = (float)bbox[(b * kN + s2) * 4 + 2];
                float y2 = (float)bbox[(b * kN + s2) * 4 + 3];
                bx[0] = fminf(fmaxf((x1 + x2) * 0.5f / kW, 0.f), 1.f);
                bx[1] = fminf(fmaxf((y1 + y2) * 0.5f / kH, 0.f), 1.f);
                bx[2] = fminf(fmaxf(fmaxf(x2 - x1, 0.f) / kW, 0.f), 1.f);
                bx[3] = fminf(fmaxf(fmaxf(y2 - y1, 0.f) / kH, 0.f), 1.f);
            }
        }
        for (int c4 = 0; c4 < 4; ++c4)
            out[O_BOX + (size_t)(b * kN + slot) * 4 + c4] = bx[c4];
    }
}

// ---------------------------------------------------------------------------
// K3: mask_logits + fused x-resize, kept-candidate slots only (< kTOPK).
// grid(kH/4, kTOPK, kB), block(256): one wave per mask row. Kept slots: read
// row once (float4), write logits (nontemporal — never re-read, keeps the
// mask lines L3-resident), stage clipped row in padded LDS (col + col>>5
// breaks the 20-way bank conflict), lanes 0..39 produce the x-resize outputs
// (identical tap weights/order → bitwise-equal S1). Slots in [count,kTOPK):
// constant -20 nt fill. Slots >= kTOPK are handled by k3f.
__global__ __launch_bounds__(256) void k3_logits_resizex(
    const float* __restrict__ masks, const int* __restrict__ src_q,
    float* __restrict__ out, float* __restrict__ S1) {
    int b = blockIdx.z, slot = blockIdx.y;
    int q = src_q[b * kN + slot];
    int lane = threadIdx.x & 63, wv = threadIdx.x >> 6;
    int y = blockIdx.x * 4 + wv;
    float4* dst = (float4*)(out + O_MASK + (size_t)(b * kN + slot) * kHW) + (size_t)y * 160;

    if (q < 0) {
        float4 f = make_float4(-20.f, -20.f, -20.f, -20.f);
        nt_store4(f, dst + lane);
        nt_store4(f, dst + 64 + lane);
        if (lane < 32) nt_store4(f, dst + 128 + lane);
        return;
    }

    __shared__ float rbuf[4][660];  // 640 + 20 pad floats per row
    const float4* src = (const float4*)(masks + (size_t)(b * kN + q) * kHW) + (size_t)y * 160;
#pragma unroll
    for (int i = 0; i < 3; ++i) {
        int idx = i * 64 + lane;
        if (idx < 160) {
            float4 m = src[idx];
            float4 o;
            o.x = logit_fast(m.x); o.y = logit_fast(m.y);
            o.z = logit_fast(m.z); o.w = logit_fast(m.w);
            nt_store4(o, dst + idx);
            int col = idx * 4;
            int pad = col >> 5;  // (col+c)>>5 == col>>5 for c in 0..3 (col%4==0)
            rbuf[wv][col + pad + 0] = fminf(fmaxf(m.x, 0.f), 1.f);
            rbuf[wv][col + pad + 1] = fminf(fmaxf(m.y, 0.f), 1.f);
            rbuf[wv][col + pad + 2] = fminf(fmaxf(m.z, 0.f), 1.f);
            rbuf[wv][col + pad + 3] = fminf(fmaxf(m.w, 0.f), 1.f);
        }
    }
    __syncthreads();
    if (lane < kFW) {
        int ox = lane;
        float c = 16.0f * ox + 7.5f;
        float s = 0.f;
#pragma unroll
        for (int t = 0; t < 32; ++t) {
            int j = 16 * ox - 8 + t;
            if (j >= 0 && j < kW) {
                float w = 1.0f - fabsf((float)j - c) * (1.0f / 16.0f);
                s += w * rbuf[wv][j + (j >> 5)];
            }
        }
        float rs = (ox == 0 || ox == kFW - 1) ? (1.0f / 14.0f) : (1.0f / 16.0f);
        S1[((size_t)(b * kTOPK + slot) * kH + y) * kFW + ox] = s * rs;
    }
}

// ---------------------------------------------------------------------------
// K3f: stream -20 into the always-invalid slot region [kTOPK, kN) — count can
// never exceed kTOPK. Pure write, nontemporal (never re-read; keeps masks in
// L3 for k3's re-read). grid(1024, kB), block(256), grid-stride float4.
__global__ __launch_bounds__(256) void k3f_fill(float* __restrict__ out) {
    int b = blockIdx.y;
    float4* base = (float4*)(out + O_MASK + ((size_t)b * kN + kTOPK) * (size_t)kHW);
    const size_t n4 = (size_t)(kN - kTOPK) * kHW / 4;  // 6,144,000 float4/image
    float4 f = make_float4(-20.f, -20.f, -20.f, -20.f);
    for (size_t i = (size_t)blockIdx.x * 256 + threadIdx.x; i < n4;
         i += (size_t)gridDim.x * 256)
        nt_store4(f, base + i);
}

// ---------------------------------------------------------------------------
// K6: resize along y (640 -> 40) + per-mask sum (denominator, via atomics —
// denom zero-initialized in K0, fmax applied at use in K7).
// grid(5, kTOPK, kB), block(256).
__global__ __launch_bounds__(256) void k6_resize_y(
    const float* __restrict__ S1, const int* __restrict__ countArr,
    float* __restrict__ msmall, float* __restrict__ denom) {
    int k = blockIdx.y, b = blockIdx.z;
    if (k >= countArr[b]) return;
    const float* src = S1 + (size_t)(b * kTOPK + k) * kH * kFW;
    int e0 = blockIdx.x * 320;
    float tot = 0.f;
    for (int ee = threadIdx.x; ee < 320; ee += 256) {
        int e = e0 + ee;
        int oy = e / kFW, ox = e % kFW;
        float c = 16.0f * oy + 7.5f;
        int j0 = max(0, 16 * oy - 8), j1 = min(kH - 1, 16 * oy + 23);
        float s = 0.f;
        for (int j = j0; j <= j1; ++j) {
            float w = 1.0f - fabsf((float)j - c) * (1.0f / 16.0f);
            s += w * src[(size_t)j * kFW + ox];
        }
        float rs = (oy == 0 || oy == kFH - 1) ? (1.0f / 14.0f) : (1.0f / 16.0f);
        s *= rs;
        msmall[(size_t)(b * kTOPK + k) * kFH * kFW + e] = s;
        tot += s;
    }
    __shared__ float sm[256];
    sm[threadIdx.x] = tot;
    __syncthreads();
    for (int st = 128; st > 0; st >>= 1) {
        if (threadIdx.x < st) sm[threadIdx.x] += sm[threadIdx.x + st];
        __syncthreads();
    }
    if (threadIdx.x == 0) atomicAdd(&denom[b * kTOPK + k], sm[0]);
}

// ---------------------------------------------------------------------------
// K7: mask-pooled features. grid(kD, kB), block(256): 4 waves per block, each
// wave caches the feature channel (25 regs/lane) and handles a k-stripe.
__global__ __launch_bounds__(256) void k7_pool(
    const float* __restrict__ feat, const float* __restrict__ msmall,
    const float* __restrict__ denom, const int* __restrict__ countArr,
    float* __restrict__ pooled) {
    int d = blockIdx.x, b = blockIdx.y;
    int lane = threadIdx.x & 63, wv = threadIdx.x >> 6;
    const float* fp = feat + ((size_t)b * kD + d) * (kFH * kFW);
    float f[25];
#pragma unroll
    for (int i = 0; i < 25; ++i) f[i] = fp[i * 64 + lane];
    int count = countArr[b];
    for (int k = wv; k < count; k += 4) {
        const float* sp = msmall + (size_t)(b * kTOPK + k) * (kFH * kFW);
        float acc = 0.f;
#pragma unroll
        for (int i = 0; i < 25; ++i) acc += f[i] * sp[i * 64 + lane];
        for (int off = 32; off > 0; off >>= 1) acc += __shfl_down(acc, off);
        if (lane == 0)
            pooled[(size_t)(b * kTOPK + k) * kD + d] =
                acc / fmaxf(denom[b * kTOPK + k], 1e-6f);
    }
}

// ---------------------------------------------------------------------------
// K8: L2-normalize pooled -> embs (zeros for invalid). grid(kN, kB), block(128).
__global__ void k8_embs(const float* __restrict__ pooled,
                        const int* __restrict__ countArr,
                        float* __restrict__ out) {
    int slot = blockIdx.x, b = blockIdx.y;
    int count = countArr[b];
    float* dst = out + O_EMB + (size_t)(b * kN + slot) * kD;
    if (slot >= count) {
        for (int e = threadIdx.x; e < kD; e += 128) dst[e] = 0.f;
        return;
    }
    const float* p = pooled + (size_t)(b * kTOPK + slot) * kD;
    float ss = 0.f;
    for (int e = threadIdx.x; e < kD; e += 128) { float v = p[e]; ss += v * v; }
    __shared__ float sm[128];
    sm[threadIdx.x] = ss;
    __syncthreads();
    for (int st = 64; st > 0; st >>= 1) {
        if (threadIdx.x < st) sm[threadIdx.x] += sm[threadIdx.x + st];
        __syncthreads();
    }
    float norm = fmaxf(sqrtf(sm[0]), 1e-12f);
    for (int e = threadIdx.x; e < kD; e += 128) dst[e] = p[e] / norm;
}

// ---------------------------------------------------------------------------
extern "C" void kernel_launch(void* const* d_in, const int* in_sizes, int n_in,
                              void* d_out, int out_size, void* d_ws, size_t ws_size,
                              hipStream_t stream) {
    const float* masks  = (const float*)d_in[0];
    const int*   labels = (const int*)d_in[1];
    const float* scores = (const float*)d_in[2];
    const float* feat   = (const float*)d_in[3];
    // d_in[4] = class_count (device scalar) — fixed at 80 per problem shape.
    float* out = (float*)d_out;

    // Workspace carve-up (~19.2 MB total)
    char* ws = (char*)d_ws;
    auto take = [&](size_t bytes) { char* p = ws; ws += (bytes + 255) & ~(size_t)255; return p; };
    unsigned long long* packed = (unsigned long long*)take((size_t)kB * kN * kWORDS * 8);
    float* S1     = (float*)take((size_t)kB * kTOPK * kH * kFW * 4);
    float* msmall = (float*)take((size_t)kB * kTOPK * kFH * kFW * 4);
    float* pooled = (float*)take((size_t)kB * kTOPK * kD * 4);
    float* sScore = (float*)take((size_t)kB * kN * 4);
    float* denom  = (float*)take((size_t)kB * kTOPK * 4);
    int* order    = (int*)take((size_t)kB * kN * 4);
    int* sLabel   = (int*)take((size_t)kB * kN * 4);
    int* area     = (int*)take((size_t)kB * kN * 4);
    int* bbox     = (int*)take((size_t)kB * kN * 4 * 4);
    int* src_q    = (int*)take((size_t)kB * kN * 4);
    int* keep_s   = (int*)take((size_t)kB * kN * 4);
    int* countArr = (int*)take((size_t)kB * 4);
    unsigned long long* confRow = (unsigned long long*)take((size_t)kB * kN * kCW * 8);
    int* pairList  = (int*)take((size_t)kB * kPairMax * 4);
    int* pairCount = (int*)take((size_t)kB * 4);

    k0_sort_init<<<dim3(kB), dim3(128), 0, stream>>>(scores, labels, order, sScore,
                                                     sLabel, area, bbox, confRow,
                                                     denom, pairList, pairCount);
    k1_pack<<<dim3(kSPLIT, kN, kB), dim3(256), 0, stream>>>(masks, order, sScore,
                                                            packed, area, bbox);
    k2a_conflict<<<dim3(512, kB), dim3(256), 0, stream>>>(packed, area, pairList,
                                                          pairCount, confRow);
    k2b_greedy_clsbox<<<dim3(kB), dim3(256), 0, stream>>>(sScore, order, confRow,
                                                          sLabel, area, bbox, src_q,
                                                          keep_s, countArr, out);
    k3_logits_resizex<<<dim3(kH / 4, kTOPK, kB), dim3(256), 0, stream>>>(masks, src_q,
                                                                         out, S1);
    k3f_fill<<<dim3(1024, kB), dim3(256), 0, stream>>>(out);
    k6_resize_y<<<dim3(5, kTOPK, kB), dim3(256), 0, stream>>>(S1, countArr, msmall,
                                                              denom);
    k7_pool<<<dim3(kD, kB), dim3(256), 0, stream>>>(feat, msmall, denom, countArr,
                                                    pooled);
    k8_embs<<<dim3(kN, kB), dim3(128), 0, stream>>>(pooled, countArr, out);
}